// Round 5
// baseline (330.069 us; speedup 1.0000x reference)
//
#include <hip/hip_runtime.h>
#include <cstdint>
#include <cstddef>

#define HID 128
#define SEQL 28
#define INP 28
#define NL 10
#define NC 10
#define BATCH 4096
#define BB 16             // batch rows per block
#define STRD 136          // padded row stride in halfs (272 B, b128-aligned)
#define BUFH (16 * STRD)  // halfs per 16x128 activation panel

typedef _Float16 half8 __attribute__((ext_vector_type(8)));
typedef float    f32x4 __attribute__((ext_vector_type(4)));

// ws layout: seq [BATCH][SEQL][HID] f16 @ 0 (group-boundary activations, in-place reuse)

__device__ __forceinline__ float tanh_fast(float v) {
  float e = __expf(2.f * v);
  return 1.f - 2.f / (e + 1.f);
}

// 512 threads = 8 waves. Groups of layers: {0-3}, {4-7}, {8-9}.
// Wave (l = wid&3, kh = wid>>2) owns ALL 128 output cols of layer l, K-half kh
// (kh=0: input projection K 0..127, kh=1: recurrent K 128..255).
// Diagonal wavefront over (l, t): tick tau runs cell (l, t=tau-l).
// Per tick: phaseA = MFMA partials (A panel read ONCE per cell, not 8x),
// partial write to pbuf; barrier; phaseB = finalize 4 tiles each (own acc +
// partner partial + bias, tanh), write O; barrier.
// LDS slots: X(p)=slot p; O(l,p)=slot 2+2l+p.
__global__ __launch_bounds__(512, 2) void rnn_fused(
    const float* __restrict__ x,
    const float* __restrict__ Wih0,
    const float* __restrict__ Wih,
    const float* __restrict__ Whh,
    const float* __restrict__ bih,
    const float* __restrict__ bhh,
    const float* __restrict__ fcW,
    const float* __restrict__ fcb,
    _Float16* __restrict__ seq,
    float* __restrict__ out) {
  __shared__ _Float16 lds[BUFH * 10] __attribute__((aligned(16)));
  __shared__ float pbuf[4 * 8 * 64 * 4] __attribute__((aligned(16)));  // 32 KB

  const int tid    = threadIdx.x;
  const int lane15 = tid & 15;        // MFMA A-row m / D-col n
  const int quad   = (tid >> 4) & 3;  // MFMA quad
  const int wid    = tid >> 6;
  const int lane   = tid & 63;
  const int b0     = blockIdx.x * BB;
  const int frow1  = tid >> 5, fseg1 = tid & 31;    // seq fill (b64, 512 thr)
  const int frow0  = tid >> 3, fc0 = (tid & 7) * 4; // x fill (128 thr)

  half8 bfrag[8][4];
  f32x4 acc[8];
  float biasf[4];
  float pfx[4]; uint2 pfu;

  for (int g = 0; g < 3; ++g) {
    const int NLg = (g < 2) ? 4 : 2;
    const int gl0 = g * 4;                    // 0, 4, 8
    const bool won = (g < 2) || (wid < 4);
    const int l  = (g < 2) ? (wid & 3) : (wid & 1);
    const int kh = (g < 2) ? (wid >> 2) : ((wid >> 1) & 1);
    const int gl = gl0 + l;

    if (won) {
      // --- stage this wave's weight half directly from f32 (L2-hot) ---
      const float* src = (kh == 1) ? (Whh + (size_t)gl * HID * HID)
                         : (gl == 0 ? Wih0 : Wih + (size_t)(gl - 1) * HID * HID);
#pragma unroll
      for (int nt = 0; nt < 8; ++nt) {
        const int n = nt * 16 + lane15;
#pragma unroll
        for (int ks = 0; ks < 4; ++ks) {
          half8 h;
          if (gl == 0 && kh == 0) {
            if (ks == 0) {
#pragma unroll
              for (int j = 0; j < 8; ++j) {
                int c = quad * 8 + j;
                h[j] = (_Float16)((c < INP) ? Wih0[n * INP + c] : 0.f);
              }
            } else {
#pragma unroll
              for (int j = 0; j < 8; ++j) h[j] = (_Float16)0.f;  // unused (nks=1)
            }
          } else {
            const float* p = src + (size_t)n * HID + ks * 32 + quad * 8;
            float4 f0 = *(const float4*)p;
            float4 f1 = *(const float4*)(p + 4);
            h[0] = (_Float16)f0.x; h[1] = (_Float16)f0.y;
            h[2] = (_Float16)f0.z; h[3] = (_Float16)f0.w;
            h[4] = (_Float16)f1.x; h[5] = (_Float16)f1.y;
            h[6] = (_Float16)f1.z; h[7] = (_Float16)f1.w;
          }
          bfrag[nt][ks] = h;
        }
      }
#pragma unroll
      for (int i = 0; i < 4; ++i) {
        int n = (kh * 4 + i) * 16 + lane15;
        biasf[i] = bih[gl * HID + n] + bhh[gl * HID + n];
      }
    }
    __syncthreads();  // prev group's LDS reads complete
    {                 // zero all 8 O slots (h=0 at t=0)
      uint4 z; z.x = z.y = z.z = z.w = 0u;
      for (int i = tid; i < (BUFH * 8) / 8; i += 512)
        ((uint4*)(lds + 2 * BUFH))[i] = z;
    }
    // prefill X(0) with t=0 input
    if (g == 0) {
      if (tid < 128) {
        const float* xb = x + ((size_t)(b0 + frow0) * SEQL + 0) * INP;
        _Float16 h4[4];
#pragma unroll
        for (int i = 0; i < 4; ++i) h4[i] = (_Float16)((fc0 + i < INP) ? xb[fc0 + i] : 0.f);
        *(uint2*)(lds + frow0 * STRD + fc0) = *(const uint2*)h4;
      }
    } else {
      uint2 v = *(const uint2*)(seq + ((size_t)(b0 + frow1) * SEQL + 0) * HID + fseg1 * 4);
      *(uint2*)(lds + frow1 * STRD + fseg1 * 4) = v;
    }
    __syncthreads();

    const int TICKS = SEQL + NLg - 1;
    for (int tau = 0; tau < TICKS; ++tau) {
      const int pt = tau & 1;
      const int t  = tau - l;
      const bool act = won && (t >= 0) && (t < SEQL);
      const bool hn  = (tau + 1) < SEQL;
      if (hn) {  // prefetch input(tau+1) into regs; latency hidden across tick
        if (g == 0) {
          if (tid < 128) {
            const float* xb = x + ((size_t)(b0 + frow0) * SEQL + (tau + 1)) * INP;
#pragma unroll
            for (int i = 0; i < 4; ++i) pfx[i] = (fc0 + i < INP) ? xb[fc0 + i] : 0.f;
          }
        } else {
          pfu = *(const uint2*)(seq + ((size_t)(b0 + frow1) * SEQL + (tau + 1)) * HID + fseg1 * 4);
        }
      }
      // ---------------- phase A: partials ----------------
      if (act) {
        const _Float16* apan = (kh == 0)
            ? ((l == 0) ? (lds + pt * BUFH) : (lds + (2 + 2 * (l - 1) + (1 - pt)) * BUFH))
            : (lds + (2 + 2 * l + (1 - pt)) * BUFH);
#pragma unroll
        for (int nt = 0; nt < 8; ++nt) acc[nt] = (f32x4){0.f, 0.f, 0.f, 0.f};
        if (g == 0 && l == 0 && kh == 0) {  // x padded to 32 cols: 1 K-chunk
          half8 a0 = *(const half8*)(apan + lane15 * STRD + quad * 8);
#pragma unroll
          for (int nt = 0; nt < 8; ++nt)
            acc[nt] = __builtin_amdgcn_mfma_f32_16x16x32_f16(a0, bfrag[nt][0], acc[nt], 0, 0, 0);
        } else {
          half8 af[4];
#pragma unroll
          for (int ks = 0; ks < 4; ++ks)
            af[ks] = *(const half8*)(apan + lane15 * STRD + ks * 32 + quad * 8);
#pragma unroll
          for (int ks = 0; ks < 4; ++ks)
#pragma unroll
            for (int nt = 0; nt < 8; ++nt)
              acc[nt] = __builtin_amdgcn_mfma_f32_16x16x32_f16(af[ks], bfrag[nt][ks], acc[nt], 0, 0, 0);
        }
        // write partials for the 4 tiles the partner finalizes (kh-uniform branch
        // keeps acc[] indices compile-time -> no scratch spill)
        if (kh == 0) {
          float* pb = pbuf + ((size_t)(l * 8 + 4) * 64 + lane) * 4;
#pragma unroll
          for (int i = 0; i < 4; ++i) *(f32x4*)(pb + (size_t)i * 256) = acc[4 + i];
        } else {
          float* pb = pbuf + ((size_t)(l * 8 + 0) * 64 + lane) * 4;
#pragma unroll
          for (int i = 0; i < 4; ++i) *(f32x4*)(pb + (size_t)i * 256) = acc[i];
        }
      }
      __syncthreads();
      // ---------------- phase B: finalize ----------------
      if (act) {
        _Float16* Ob = lds + (2 + 2 * l + pt) * BUFH;
        const bool wr_seq = (g < 2) && (l == NLg - 1);
        if (kh == 0) {
#pragma unroll
          for (int i = 0; i < 4; ++i) {
            const int nt = i;
            f32x4 p = *(const f32x4*)(pbuf + ((size_t)(l * 8 + nt) * 64 + lane) * 4);
            const int n = nt * 16 + lane15;
#pragma unroll
            for (int r = 0; r < 4; ++r) {
              float v = tanh_fast(acc[nt][r] + p[r] + biasf[i]);
              const int m = quad * 4 + r;
              Ob[m * STRD + n] = (_Float16)v;
              if (wr_seq) seq[((size_t)(b0 + m) * SEQL + t) * HID + n] = (_Float16)v;
            }
          }
        } else {
#pragma unroll
          for (int i = 0; i < 4; ++i) {
            const int nt = 4 + i;
            f32x4 p = *(const f32x4*)(pbuf + ((size_t)(l * 8 + nt) * 64 + lane) * 4);
            const int n = nt * 16 + lane15;
#pragma unroll
            for (int r = 0; r < 4; ++r) {
              float v = tanh_fast(acc[nt][r] + p[r] + biasf[i]);
              const int m = quad * 4 + r;
              Ob[m * STRD + n] = (_Float16)v;
              if (wr_seq) seq[((size_t)(b0 + m) * SEQL + t) * HID + n] = (_Float16)v;
            }
          }
        }
      }
      if (hn) {  // store prefetched input into X(1-pt); read next tick phase A
        if (g == 0) {
          if (tid < 128) {
            _Float16 h4[4];
#pragma unroll
            for (int i = 0; i < 4; ++i) h4[i] = (_Float16)pfx[i];
            *(uint2*)(lds + (1 - pt) * BUFH + frow0 * STRD + fc0) = *(const uint2*)h4;
          }
        } else {
          *(uint2*)(lds + (1 - pt) * BUFH + frow1 * STRD + fseg1 * 4) = pfu;
        }
      }
      __syncthreads();
    }
  }

  // --- FC on layer-9 h at t=27: G2 local l=1, tick 28 (pt=0) -> slot 2+2+0=4 ---
  if (tid < BB * NC) {
    int c = tid >> 4;
    int b = tid & 15;
    float a = fcb[c];
    const float* wr = fcW + c * HID;
    const _Float16* hr = lds + 4 * BUFH + b * STRD;
#pragma unroll 4
    for (int k = 0; k < HID; ++k) a += (float)hr[k] * wr[k];
    out[(size_t)(b0 + b) * NC + c] = a;
  }
}

extern "C" void kernel_launch(void* const* d_in, const int* in_sizes, int n_in,
                              void* d_out, int out_size, void* d_ws, size_t ws_size,
                              hipStream_t stream) {
  const float* x    = (const float*)d_in[0];
  const float* Wih0 = (const float*)d_in[1];
  const float* Wih  = (const float*)d_in[2];
  const float* Whh  = (const float*)d_in[3];
  const float* bih  = (const float*)d_in[4];
  const float* bhh  = (const float*)d_in[5];
  const float* fcW  = (const float*)d_in[6];
  const float* fcb  = (const float*)d_in[7];
  float* out = (float*)d_out;
  _Float16* seq = (_Float16*)d_ws;

  rnn_fused<<<dim3(BATCH / BB), dim3(512), 0, stream>>>(
      x, Wih0, Wih, Whh, bih, bhh, fcW, fcb, seq, out);
}

// Round 6
// 267.640 us; speedup vs baseline: 1.2333x; 1.2333x over previous
//
#include <hip/hip_runtime.h>
#include <cstdint>
#include <cstddef>

#define HID 128
#define SEQL 28
#define INP 28
#define NL 10
#define NC 10
#define BATCH 4096
#define BB 16             // batch rows per block
#define STRD 136          // padded row stride in halfs (272 B, b128-aligned)
#define BUFH (16 * STRD)  // halfs per 16x128 activation panel

typedef _Float16 half8 __attribute__((ext_vector_type(8)));
typedef float    f32x4 __attribute__((ext_vector_type(4)));

// ws: seq [BATCH][SEQL][HID] f16 @ 0 (group-boundary activations, in-place reuse)

__device__ __forceinline__ float tanh_fast(float v) {
  float e = __expf(2.f * v);
  return 1.f - 2.f / (e + 1.f);
}

// 512 threads = 8 waves. Layer groups {0-3},{4-7},{8-9}.
// G0/G1: wave = (l = wid&3, colhalf = wid>>2): owns layer l, 4 n-tiles, K=256.
// G2   : wave = (l = wid&1, colquarter = wid>>1): owns layer l, 2 n-tiles.
// No k-split -> no partial exchange -> ONE barrier per tick (round-5 lesson).
// Diagonal wavefront: tick tau runs cell (l, t = tau - l).
// MFMA operands SWAPPED vs rounds 1-5: A = weight frag (row=n), B = activation
// frag (col=batch row m) -> D: col(lane15)=m, row(quad*4+r)=n -> each lane's 4
// outputs are 4 consecutive n of one batch row -> b64 epilogue writes.
// LDS slots (BUFH each): X(p)=slot p; O(l,p)=slot 2+2l+p.
__global__ __launch_bounds__(512, 2) void rnn_fused(
    const float* __restrict__ x,
    const float* __restrict__ Wih0,
    const float* __restrict__ Wih,
    const float* __restrict__ Whh,
    const float* __restrict__ bih,
    const float* __restrict__ bhh,
    const float* __restrict__ fcW,
    const float* __restrict__ fcb,
    _Float16* __restrict__ seq,
    float* __restrict__ out) {
  __shared__ _Float16 lds[BUFH * 10] __attribute__((aligned(16)));

  const int tid    = threadIdx.x;
  const int lane15 = tid & 15;        // frag row/col index
  const int quad   = (tid >> 4) & 3;  // frag k-chunk / D row group
  const int wid    = tid >> 6;
  const int b0     = blockIdx.x * BB;
  const int frow1  = tid >> 5, fseg1 = tid & 31;     // seq fill (512 thr, b64)
  const int frow0  = tid >> 3, fc0 = (tid & 7) * 4;  // x fill (128 thr)

  half8 bfrag[4][8];     // [n-tile][k-chunk] weight A-frags
  float biasv[4][4];     // [n-tile][r]  (n = tile*16 + quad*4 + r)
  f32x4 acc[4];
  float pfx[4]; uint2 pfu;

  for (int g = 0; g < 3; ++g) {
    const int NLg = (g < 2) ? 4 : 2;
    const int l   = (g < 2) ? (wid & 3) : (wid & 1);
    const int NT  = (g < 2) ? 4 : 2;
    const int tb  = ((g < 2) ? (wid >> 2) : (wid >> 1)) * NT;  // first n-tile
    const int gl  = g * 4 + l;                                  // global layer

    // --- stage this wave's weights (Wih|Whh, K=256) as A-frags, f32->f16 ---
    const float* WihS = (gl == 0) ? Wih0 : Wih + (size_t)(gl - 1) * HID * HID;
    const float* WhhS = Whh + (size_t)gl * HID * HID;
#pragma unroll
    for (int nt = 0; nt < 4; ++nt) if (nt < NT) {
      const int n = (tb + nt) * 16 + lane15;
#pragma unroll
      for (int ks = 0; ks < 8; ++ks) {
        half8 h;
        if (gl == 0 && ks < 4) {           // layer 0: x padded to 32 cols
          if (ks == 0) {
#pragma unroll
            for (int j = 0; j < 8; ++j) {
              int c = quad * 8 + j;
              h[j] = (_Float16)((c < INP) ? Wih0[n * INP + c] : 0.f);
            }
          } else {
#pragma unroll
            for (int j = 0; j < 8; ++j) h[j] = (_Float16)0.f;  // never used
          }
        } else {
          const float* p = (ks < 4) ? (WihS + (size_t)n * HID + ks * 32 + quad * 8)
                                    : (WhhS + (size_t)n * HID + (ks - 4) * 32 + quad * 8);
          float4 f0 = *(const float4*)p;
          float4 f1 = *(const float4*)(p + 4);
          h[0] = (_Float16)f0.x; h[1] = (_Float16)f0.y;
          h[2] = (_Float16)f0.z; h[3] = (_Float16)f0.w;
          h[4] = (_Float16)f1.x; h[5] = (_Float16)f1.y;
          h[6] = (_Float16)f1.z; h[7] = (_Float16)f1.w;
        }
        bfrag[nt][ks] = h;
      }
#pragma unroll
      for (int r = 0; r < 4; ++r) {
        int nn = (tb + nt) * 16 + quad * 4 + r;
        biasv[nt][r] = bih[gl * HID + nn] + bhh[gl * HID + nn];
      }
    }
    __syncthreads();  // prev group's LDS reads complete before re-zeroing
    {                 // zero all O slots (h = 0 at t = 0)
      uint4 z; z.x = z.y = z.z = z.w = 0u;
      for (int i = tid; i < (BUFH * 8) / 8; i += 512)
        ((uint4*)(lds + 2 * BUFH))[i] = z;
    }
    // prefill X(0) with t=0 input (visible after tick-0 barrier)
    if (g == 0) {
      if (tid < 128) {
        const float* xb = x + ((size_t)(b0 + frow0) * SEQL + 0) * INP;
        _Float16 h4[4];
#pragma unroll
        for (int i = 0; i < 4; ++i)
          h4[i] = (_Float16)((fc0 + i < INP) ? xb[fc0 + i] : 0.f);
        *(uint2*)(lds + frow0 * STRD + fc0) = *(const uint2*)h4;
      }
    } else {
      uint2 v = *(const uint2*)(seq + ((size_t)(b0 + frow1) * SEQL + 0) * HID + fseg1 * 4);
      *(uint2*)(lds + frow1 * STRD + fseg1 * 4) = v;
    }

    const int TICKS = SEQL + NLg - 1;
    for (int tau = 0; tau < TICKS; ++tau) {
      __syncthreads();                 // single barrier per tick
      const int pt = tau & 1;
      const int t  = tau - l;
      const bool act = (t >= 0) && (t < SEQL);
      const bool hn  = (tau + 1) < SEQL;
      if (hn) {  // prefetch input(tau+1) into regs; whole tick to complete
        if (g == 0) {
          if (tid < 128) {
            const float* xb = x + ((size_t)(b0 + frow0) * SEQL + (tau + 1)) * INP;
#pragma unroll
            for (int i = 0; i < 4; ++i) pfx[i] = (fc0 + i < INP) ? xb[fc0 + i] : 0.f;
          }
        } else {
          pfu = *(const uint2*)(seq + ((size_t)(b0 + frow1) * SEQL + (tau + 1)) * HID + fseg1 * 4);
        }
      }
      if (act) {
        const _Float16* INb = (l == 0) ? lds + pt * BUFH
                                       : lds + (2 + 2 * (l - 1) + (1 - pt)) * BUFH;
        const _Float16* Hb  = lds + (2 + 2 * l + (1 - pt)) * BUFH;
        _Float16*       Ob  = lds + (2 + 2 * l + pt) * BUFH;

        // B-frags (activations): col = lane15 = batch row, k = ks*32+quad*8
        half8 af[8];
        if (gl != 0) {
#pragma unroll
          for (int ks = 0; ks < 4; ++ks)
            af[ks] = *(const half8*)(INb + lane15 * STRD + ks * 32 + quad * 8);
        } else {
          af[0] = *(const half8*)(INb + lane15 * STRD + quad * 8);
        }
#pragma unroll
        for (int ks = 0; ks < 4; ++ks)
          af[4 + ks] = *(const half8*)(Hb + lane15 * STRD + ks * 32 + quad * 8);

#pragma unroll
        for (int nt = 0; nt < 4; ++nt) if (nt < NT)
          acc[nt] = (f32x4){biasv[nt][0], biasv[nt][1], biasv[nt][2], biasv[nt][3]};
        if (gl != 0) {
#pragma unroll
          for (int ks = 0; ks < 4; ++ks)
#pragma unroll
            for (int nt = 0; nt < 4; ++nt) if (nt < NT)
              acc[nt] = __builtin_amdgcn_mfma_f32_16x16x32_f16(bfrag[nt][ks], af[ks], acc[nt], 0, 0, 0);
        } else {
#pragma unroll
          for (int nt = 0; nt < 4; ++nt) if (nt < NT)
            acc[nt] = __builtin_amdgcn_mfma_f32_16x16x32_f16(bfrag[nt][0], af[0], acc[nt], 0, 0, 0);
        }
#pragma unroll
        for (int ks = 0; ks < 4; ++ks)
#pragma unroll
          for (int nt = 0; nt < 4; ++nt) if (nt < NT)
            acc[nt] = __builtin_amdgcn_mfma_f32_16x16x32_f16(bfrag[nt][4 + ks], af[4 + ks], acc[nt], 0, 0, 0);

        // epilogue: lane holds O[m=lane15][n4..n4+4) per tile -> b64 writes
        const bool wr_seq = (g < 2) && (l == NLg - 1);
#pragma unroll
        for (int nt = 0; nt < 4; ++nt) if (nt < NT) {
          _Float16 h4[4];
#pragma unroll
          for (int r = 0; r < 4; ++r) h4[r] = (_Float16)tanh_fast(acc[nt][r]);
          const int n4 = (tb + nt) * 16 + quad * 4;
          *(uint2*)(Ob + lane15 * STRD + n4) = *(const uint2*)h4;
          if (wr_seq)
            *(uint2*)(seq + ((size_t)(b0 + lane15) * SEQL + t) * HID + n4) = *(const uint2*)h4;
        }
      }
      if (hn) {  // store prefetched input into X(1-pt); read next tick
        if (g == 0) {
          if (tid < 128) {
            _Float16 h4[4];
#pragma unroll
            for (int i = 0; i < 4; ++i) h4[i] = (_Float16)pfx[i];
            *(uint2*)(lds + (1 - pt) * BUFH + frow0 * STRD + fc0) = *(const uint2*)h4;
          }
        } else {
          *(uint2*)(lds + (1 - pt) * BUFH + frow1 * STRD + fseg1 * 4) = pfu;
        }
      }
    }
  }
  __syncthreads();

  // --- FC on layer-9 h at t=27: G2 local l=1, tick 28 (pt=0) -> slot 2+2+0=4 ---
  if (tid < BB * NC) {
    int c = tid >> 4;
    int b = tid & 15;
    float a = fcb[c];
    const float* wr = fcW + c * HID;
    const _Float16* hr = lds + 4 * BUFH + b * STRD;
#pragma unroll 4
    for (int k = 0; k < HID; ++k) a += (float)hr[k] * wr[k];
    out[(size_t)(b0 + b) * NC + c] = a;
  }
}

extern "C" void kernel_launch(void* const* d_in, const int* in_sizes, int n_in,
                              void* d_out, int out_size, void* d_ws, size_t ws_size,
                              hipStream_t stream) {
  const float* x    = (const float*)d_in[0];
  const float* Wih0 = (const float*)d_in[1];
  const float* Wih  = (const float*)d_in[2];
  const float* Whh  = (const float*)d_in[3];
  const float* bih  = (const float*)d_in[4];
  const float* bhh  = (const float*)d_in[5];
  const float* fcW  = (const float*)d_in[6];
  const float* fcb  = (const float*)d_in[7];
  float* out = (float*)d_out;
  _Float16* seq = (_Float16*)d_ws;

  rnn_fused<<<dim3(BATCH / BB), dim3(512), 0, stream>>>(
      x, Wih0, Wih, Whh, bih, bhh, fcW, fcb, seq, out);
}